// Round 8
// baseline (132.741 us; speedup 1.0000x reference)
//
#include <hip/hip_runtime.h>
#include <math.h>

#define TT 128
#define IN_CH 32
#define NPATH 256
#define SIGCH 7380
#define K1 29520
#define N1 512
#define N2 256
#define BKW 12

// ---------------- Kernel 1: conv + time-augment + depth-4 signature ----------------
// One block per path; 243 threads own 3 triples each, fully independent scans
// (no barriers after dx staging). Output TRANSPOSED: sigT[k][b] so gemm1 can
// read 16 consecutive rows as one 64B line via wave-uniform scalar loads.
__global__ __launch_bounds__(256, 1) void sig_kernel(const float* __restrict__ x,
        const float* __restrict__ cw, const float* __restrict__ cb,
        float* __restrict__ sigT /*[29520][64]*/) {
    __shared__ float inc[TT][12];
    const int p = blockIdx.x;
    const int b = p >> 2, oc = p & 3;
    const int tid = threadIdx.x;

    const float4 wv = *(const float4*)(cw + oc * 4);
    const float bias = cb[oc];
    const float* xb = x + (long)b * TT * IN_CH;

    for (int it = tid; it < TT * 8; it += 256) {
        const int t = it >> 3, ch = it & 7;
        const float4 xa = *(const float4*)(xb + t * IN_CH + ch * 4);
        float v = xa.x * wv.x + xa.y * wv.y + xa.z * wv.z + xa.w * wv.w + bias;
        if (t > 0) {
            const float4 xm = *(const float4*)(xb + (t - 1) * IN_CH + ch * 4);
            v -= xm.x * wv.x + xm.y * wv.y + xm.z * wv.z + xm.w * wv.w + bias;
        }
        inc[t][1 + ch] = v;
    }
    for (int t = tid; t < TT; t += 256) inc[t][0] = t ? (1.f / 127.f) : 0.f;
    __syncthreads();

    if (tid >= 243) return;

    const int base3 = 3 * tid;
    const int i1 = base3 / 81;
    const int i2 = (base3 / 9) % 9;
    const int i30 = base3 % 9;

    float S4[3][9] = {};
    float s3[3] = {0.f, 0.f, 0.f};
    float s2 = 0.f, s1 = 0.f;

    float4 A0 = *(const float4*)&inc[0][0];
    float4 A1 = *(const float4*)&inc[0][4];
    float A2 = inc[0][8];
    float e1 = inc[0][i1], e2 = inc[0][i2];
    float f0 = inc[0][i30], f1 = inc[0][i30 + 1], f2 = inc[0][i30 + 2];

#pragma unroll 2
    for (int t = 0; t < TT; ++t) {
        const int tn = (t + 1) & (TT - 1);
        const float4 nA0 = *(const float4*)&inc[tn][0];
        const float4 nA1 = *(const float4*)&inc[tn][4];
        const float nA2 = inc[tn][8];
        const float ne1 = inc[tn][i1], ne2 = inc[tn][i2];
        const float nf0 = inc[tn][i30], nf1 = inc[tn][i30 + 1], nf2 = inc[tn][i30 + 2];

        const float t12 = e1 * e2;
        const float s1d2 = s1 * e2;
        const float Ak = t12 * (1.f / 24.f) + s1d2 * (1.f / 6.f) + s2 * 0.5f;
        const float Bk = t12 * (1.f / 6.f) + s1d2 * 0.5f + s2;

        const float K0 = f0 * Ak + s3[0];
        const float K1v = f1 * Ak + s3[1];
        const float K2v = f2 * Ak + s3[2];

#define UPD(Q, KK) \
        S4[Q][0] += (KK) * A0.x; S4[Q][1] += (KK) * A0.y; \
        S4[Q][2] += (KK) * A0.z; S4[Q][3] += (KK) * A0.w; \
        S4[Q][4] += (KK) * A1.x; S4[Q][5] += (KK) * A1.y; \
        S4[Q][6] += (KK) * A1.z; S4[Q][7] += (KK) * A1.w; \
        S4[Q][8] += (KK) * A2;
        UPD(0, K0) UPD(1, K1v) UPD(2, K2v)
#undef UPD

        s3[0] += Bk * f0; s3[1] += Bk * f1; s3[2] += Bk * f2;
        s2 += e2 * (0.5f * e1 + s1);
        s1 += e1;

        A0 = nA0; A1 = nA1; A2 = nA2;
        e1 = ne1; e2 = ne2; f0 = nf0; f1 = nf1; f2 = nf2;
    }

    float* sp = sigT + (long)oc * SIGCH * 64 + b;
    if (i2 == 0 && i30 == 0) sp[(long)i1 * 64] = s1;
    if (i30 == 0) sp[(long)(9 + base3 / 9) * 64] = s2;
    sp[(long)(90 + base3 + 0) * 64] = s3[0];
    sp[(long)(90 + base3 + 1) * 64] = s3[1];
    sp[(long)(90 + base3 + 2) * 64] = s3[2];
#pragma unroll
    for (int q = 0; q < 3; q++)
#pragma unroll
        for (int l = 0; l < 9; l++)
            sp[(long)(819 + (base3 + q) * 9 + l) * 64] = S4[q][l];
}

// ---------------- Kernel 2: GEMM1 partials, zero-LDS one-wave blocks ----------------
// Wave = 16 rows x 128 cols. z (wave-uniform) via scalar loads -> SMEM pipe is
// the ONLY lgkmcnt user (no ds_read to force lgkmcnt(0) drains). w lives in
// VGPRs: named double-buffered arrays, all compile-time indices; per k one
// coalesced global_load_dwordx2 (512B/wave), vmcnt-pipelined under compute.
// No LDS, no barriers. Grid = 4 rowgroups x 4 colgroups x ksplit waves.
__global__ __launch_bounds__(64) void gemm1_kernel(const float* __restrict__ sigT,
        const float* __restrict__ w0, float* __restrict__ part, int KCH) {
    const int rg = blockIdx.x & 3;
    const int cg = blockIdx.x >> 2;
    const int kc = blockIdx.y;
    const int n0 = cg * 128, k0 = kc * KCH, r0 = rg * 16;
    const int lane = threadIdx.x;
    const int c2 = lane * 2;

    const float* zbase = sigT + r0;                 // z[k][i] = zbase[k*64+i]
    const float* wbase = w0 + (long)k0 * N1 + n0 + c2;

    float2 wA[BKW], wB[BKW];
    float acc[16][2] = {};

#pragma unroll
    for (int k = 0; k < BKW; k++)
        wA[k] = *(const float2*)(wbase + (long)k * N1);

    const int NT = KCH / BKW;

#define COMPUTE(W, KZ) \
    _Pragma("unroll") \
    for (int k = 0; k < BKW; k++) { \
        const float4* zp = (const float4*)(zbase + (KZ) + (long)k * 64); \
        const float4 za = zp[0], zb = zp[1], zc = zp[2], zd = zp[3]; \
        const float2 wf = W[k]; \
        acc[0][0]  += za.x * wf.x; acc[0][1]  += za.x * wf.y; \
        acc[1][0]  += za.y * wf.x; acc[1][1]  += za.y * wf.y; \
        acc[2][0]  += za.z * wf.x; acc[2][1]  += za.z * wf.y; \
        acc[3][0]  += za.w * wf.x; acc[3][1]  += za.w * wf.y; \
        acc[4][0]  += zb.x * wf.x; acc[4][1]  += zb.x * wf.y; \
        acc[5][0]  += zb.y * wf.x; acc[5][1]  += zb.y * wf.y; \
        acc[6][0]  += zb.z * wf.x; acc[6][1]  += zb.z * wf.y; \
        acc[7][0]  += zb.w * wf.x; acc[7][1]  += zb.w * wf.y; \
        acc[8][0]  += zc.x * wf.x; acc[8][1]  += zc.x * wf.y; \
        acc[9][0]  += zc.y * wf.x; acc[9][1]  += zc.y * wf.y; \
        acc[10][0] += zc.z * wf.x; acc[10][1] += zc.z * wf.y; \
        acc[11][0] += zc.w * wf.x; acc[11][1] += zc.w * wf.y; \
        acc[12][0] += zd.x * wf.x; acc[12][1] += zd.x * wf.y; \
        acc[13][0] += zd.y * wf.x; acc[13][1] += zd.y * wf.y; \
        acc[14][0] += zd.z * wf.x; acc[14][1] += zd.z * wf.y; \
        acc[15][0] += zd.w * wf.x; acc[15][1] += zd.w * wf.y; \
    }

    for (int tile = 0; tile < NT; ++tile) {
        const long kz = (long)(k0 + tile * BKW) * 64;
        const float* wnext = wbase + (long)(tile + 1) * BKW * N1;
        if (tile & 1) {
            if (tile + 1 < NT) {
#pragma unroll
                for (int k = 0; k < BKW; k++)
                    wA[k] = *(const float2*)(wnext + (long)k * N1);
            }
            COMPUTE(wB, kz)
        } else {
            if (tile + 1 < NT) {
#pragma unroll
                for (int k = 0; k < BKW; k++)
                    wB[k] = *(const float2*)(wnext + (long)k * N1);
            }
            COMPUTE(wA, kz)
        }
    }
#undef COMPUTE

    float* pp = part + ((long)kc * 64 + r0) * N1 + n0 + c2;
#pragma unroll
    for (int r = 0; r < 16; r++)
        *(float2*)(pp + (long)r * N1) = make_float2(acc[r][0], acc[r][1]);
}

// ---------------- Kernel 3: reduce partials + bias + sigmoid ----------------
__global__ __launch_bounds__(256) void red1_kernel(const float* __restrict__ part,
        const float* __restrict__ b0v, float* __restrict__ z1, int ksplit) {
    __shared__ float4 red[256];
    const int tid = threadIdx.x;
    const int g = tid & 31, s = tid >> 5;
    const int gg = blockIdx.x * 32 + g;
    const int per = (ksplit + 7) >> 3;
    const int ks = s * per, ke = min(ksplit, ks + per);
    float4 a = make_float4(0.f, 0.f, 0.f, 0.f);
    for (int kc = ks; kc < ke; kc++) {
        float4 pv = *(const float4*)(part + ((long)kc * 8192 + gg) * 4);
        a.x += pv.x; a.y += pv.y; a.z += pv.z; a.w += pv.w;
    }
    red[tid] = a;
    __syncthreads();
    if (tid < 128) { float4 o = red[tid + 128]; red[tid].x += o.x; red[tid].y += o.y; red[tid].z += o.z; red[tid].w += o.w; }
    __syncthreads();
    if (tid < 64) { float4 o = red[tid + 64]; red[tid].x += o.x; red[tid].y += o.y; red[tid].z += o.z; red[tid].w += o.w; }
    __syncthreads();
    if (tid < 32) {
        float4 sum = red[tid];
        float4 o = red[tid + 32];
        sum.x += o.x; sum.y += o.y; sum.z += o.z; sum.w += o.w;
        const float4 bv = *(const float4*)(b0v + (gg & 127) * 4);
        float4 r;
        r.x = 1.f / (1.f + expf(-(sum.x + bv.x)));
        r.y = 1.f / (1.f + expf(-(sum.y + bv.y)));
        r.z = 1.f / (1.f + expf(-(sum.z + bv.z)));
        r.w = 1.f / (1.f + expf(-(sum.w + bv.w)));
        *(float4*)(z1 + gg * 4) = r;
    }
}

// ---------------- Kernel 4: GEMM2 + bias + sigmoid (in-block K-split) ----------------
__global__ __launch_bounds__(256) void gemm2_kernel(const float* __restrict__ z1,
        const float* __restrict__ w1, const float* __restrict__ b1v,
        float* __restrict__ z2) {
    __shared__ float red[256];
    const int m = blockIdx.x >> 2, nq = blockIdx.x & 3;
    const int tid = threadIdx.x;
    const int c = tid & 63, s = tid >> 6;
    const int n = nq * 64 + c;
    const float* zr = z1 + m * N1 + s * 128;
    const float* wr = w1 + (long)(s * 128) * N2 + n;
    float acc = 0.f;
#pragma unroll 16
    for (int k = 0; k < 128; k++) acc += zr[k] * wr[(long)k * N2];
    red[tid] = acc;
    __syncthreads();
    if (tid < 128) red[tid] += red[tid + 128];
    __syncthreads();
    if (tid < 64) {
        float sum = red[tid] + red[tid + 64] + b1v[n];
        z2[m * N2 + n] = 1.f / (1.f + expf(-sum));
    }
}

// ---------------- Kernel 5: GEMM3 + log_softmax ----------------
__global__ __launch_bounds__(64) void head_kernel(const float* __restrict__ z2,
        const float* __restrict__ w2, const float* __restrict__ b2v,
        float* __restrict__ out) {
    const int m = blockIdx.x;
    const int tid = threadIdx.x;
    __shared__ float logits[10];
    if (tid < 10) {
        float s = b2v[tid];
        const float* zr = z2 + m * N2;
#pragma unroll 8
        for (int k = 0; k < N2; k++) s += zr[k] * w2[k * 10 + tid];
        logits[tid] = s;
    }
    __syncthreads();
    if (tid == 0) {
        float mx = logits[0];
        for (int j = 1; j < 10; j++) mx = fmaxf(mx, logits[j]);
        float sum = 0.f;
        for (int j = 0; j < 10; j++) sum += expf(logits[j] - mx);
        const float lse = mx + logf(sum);
        for (int j = 0; j < 10; j++) out[m * 10 + j] = logits[j] - lse;
    }
}

extern "C" void kernel_launch(void* const* d_in, const int* in_sizes, int n_in,
                              void* d_out, int out_size, void* d_ws, size_t ws_size,
                              hipStream_t stream) {
    const float* x  = (const float*)d_in[0];
    const float* cw = (const float*)d_in[1];
    const float* cb = (const float*)d_in[2];
    const float* w0 = (const float*)d_in[3];
    const float* b0 = (const float*)d_in[4];
    const float* w1 = (const float*)d_in[5];
    const float* b1 = (const float*)d_in[6];
    const float* w2 = (const float*)d_in[7];
    const float* b2 = (const float*)d_in[8];

    // tiered K-split by workspace: 29520 = ksplit * KCH, KCH % 12 == 0
    const size_t fixed = (size_t)NPATH * SIGCH + 64 * N1 + 64 * N2;
    int ksplit = 82, kch = 360;
    if (ws_size >= (fixed + (size_t)164 * 64 * N1) * 4)      { ksplit = 164; kch = 180; }
    else if (ws_size >= (fixed + (size_t)123 * 64 * N1) * 4) { ksplit = 123; kch = 240; }

    float* ws   = (float*)d_ws;
    float* sigT = ws;                                // 29520 x 64 (transposed)
    float* part = sigT + (long)NPATH * SIGCH;        // ksplit*64*512
    float* z1   = part + (long)ksplit * 64 * N1;     // 64*512
    float* z2   = z1 + 64 * N1;                      // 64*256
    float* out  = (float*)d_out;

    sig_kernel<<<NPATH, 256, 0, stream>>>(x, cw, cb, sigT);
    gemm1_kernel<<<dim3(16, ksplit), 64, 0, stream>>>(sigT, w0, part, kch);
    red1_kernel<<<256, 256, 0, stream>>>(part, b0, z1, ksplit);
    gemm2_kernel<<<256, 256, 0, stream>>>(z1, w1, b1, z2);
    head_kernel<<<64, 64, 0, stream>>>(z2, w2, b2, out);
}

// Round 9
// 97.565 us; speedup vs baseline: 1.3605x; 1.3605x over previous
//
#include <hip/hip_runtime.h>
#include <math.h>

#define TT 128
#define IN_CH 32
#define NPATH 256
#define SIGCH 7380
#define K1 29520
#define N1 512
#define N2 256
#define BG 8

// ---------------- Kernel 1: conv + time-augment + depth-4 signature ----------------
// Transposed LDS layout incT[9][132]: e/f loads vectorize to 1 ds_read_b128
// per 4 steps each; the block-uniform increment 9-vector A is gathered with a
// single b128 (lane c<9 reads row c; others clamp to row 8 = broadcast) and
// distributed via v_readlane into SGPRs -> off the LDS pipe entirely.
// Row stride 132: bank = (4*row + t) % 32 -> <=2-way aliasing (free).
__global__ __launch_bounds__(256, 1) void sig_kernel(const float* __restrict__ x,
        const float* __restrict__ cw, const float* __restrict__ cb,
        float* __restrict__ sigT /*[29520][64]*/) {
    __shared__ float incT[9][132];
    const int p = blockIdx.x;
    const int b = p >> 2, oc = p & 3;
    const int tid = threadIdx.x;

    const float4 wv = *(const float4*)(cw + oc * 4);
    const float bias = cb[oc];
    const float* xb = x + (long)b * TT * IN_CH;

    for (int it = tid; it < TT * 8; it += 256) {
        const int t = it >> 3, ch = it & 7;
        const float4 xa = *(const float4*)(xb + t * IN_CH + ch * 4);
        float v = xa.x * wv.x + xa.y * wv.y + xa.z * wv.z + xa.w * wv.w + bias;
        if (t > 0) {
            const float4 xm = *(const float4*)(xb + (t - 1) * IN_CH + ch * 4);
            v -= xm.x * wv.x + xm.y * wv.y + xm.z * wv.z + xm.w * wv.w + bias;
        }
        incT[1 + ch][t] = v;
    }
    for (int t = tid; t < TT; t += 256) incT[0][t] = t ? (1.f / 127.f) : 0.f;
    __syncthreads();

    if (tid >= 243) return;

    const int base3 = 3 * tid;
    const int i1 = base3 / 81;
    const int i2 = (base3 / 9) % 9;
    const int i30 = base3 % 9;           // {0,3,6}, i30+2 <= 8
    const int lane = tid & 63;
    const int grow = min(lane, 8);

    float S4[3][9] = {};
    float s3[3] = {0.f, 0.f, 0.f};
    float s2 = 0.f, s1 = 0.f;

#define LD(R, T4) (*(const float4*)&incT[(R)][(T4)])
#define RL(XV, C) __int_as_float(__builtin_amdgcn_readlane(__float_as_int(XV), (C)))
#define STEP(GJ, E1, E2, F0, F1, F2) do { \
    const float t12 = (E1) * (E2); \
    const float s1d2 = s1 * (E2); \
    const float Ak = t12 * (1.f / 24.f) + s1d2 * (1.f / 6.f) + s2 * 0.5f; \
    const float Bk = t12 * (1.f / 6.f) + s1d2 * 0.5f + s2; \
    const float K0 = (F0) * Ak + s3[0]; \
    const float K1v = (F1) * Ak + s3[1]; \
    const float K2v = (F2) * Ak + s3[2]; \
    _Pragma("unroll") \
    for (int c = 0; c < 9; ++c) { \
        const float Ac = RL(GJ, c); \
        S4[0][c] += K0 * Ac; S4[1][c] += K1v * Ac; S4[2][c] += K2v * Ac; \
    } \
    s3[0] += Bk * (F0); s3[1] += Bk * (F1); s3[2] += Bk * (F2); \
    s2 += (E2) * (0.5f * (E1) + s1); \
    s1 += (E1); \
} while (0)

    float4 gA = LD(grow, 0), e1v = LD(i1, 0), e2v = LD(i2, 0);
    float4 f0v = LD(i30, 0), f1v = LD(i30 + 1, 0), f2v = LD(i30 + 2, 0);

    for (int g = 0; g < 32; ++g) {
        const int t4 = ((g + 1) & 31) * 4;            // last prefetch dummy
        const float4 ngA = LD(grow, t4);
        const float4 ne1 = LD(i1, t4), ne2 = LD(i2, t4);
        const float4 nf0 = LD(i30, t4), nf1 = LD(i30 + 1, t4), nf2 = LD(i30 + 2, t4);

        STEP(gA.x, e1v.x, e2v.x, f0v.x, f1v.x, f2v.x);
        STEP(gA.y, e1v.y, e2v.y, f0v.y, f1v.y, f2v.y);
        STEP(gA.z, e1v.z, e2v.z, f0v.z, f1v.z, f2v.z);
        STEP(gA.w, e1v.w, e2v.w, f0v.w, f1v.w, f2v.w);

        gA = ngA; e1v = ne1; e2v = ne2; f0v = nf0; f1v = nf1; f2v = nf2;
    }
#undef STEP
#undef RL
#undef LD

    float* sp = sigT + (long)oc * SIGCH * 64 + b;
    if (i2 == 0 && i30 == 0) sp[(long)i1 * 64] = s1;
    if (i30 == 0) sp[(long)(9 + base3 / 9) * 64] = s2;
    sp[(long)(90 + base3 + 0) * 64] = s3[0];
    sp[(long)(90 + base3 + 1) * 64] = s3[1];
    sp[(long)(90 + base3 + 2) * 64] = s3[2];
#pragma unroll
    for (int q = 0; q < 3; q++)
#pragma unroll
        for (int l = 0; l < 9; l++)
            sp[(long)(819 + (base3 + q) * 9 + l) * 64] = S4[q][l];
}

// ---------------- Kernel 2: GEMM1 partials ----------------
// One 512-thread block owns the FULL 64x512 tile; grid = pure k-split
// (~1 block/CU, 8 waves = 2/SIMD). Wave w owns rows 8w..8w+7; per BK=8 tile:
// (a) 16 wave-uniform z float4s -> s_load regs, ONE lgkm drain;
// (b) pure-ds_read k-loop: 2 conflict-free ds_read_b128 (per-lane float4
//     arrays wtA/wtB) per 128 FMA/lane -> LDS ratio 0.375, VALU-bound.
// w0 read exactly once; reg->LDS double buffer, one barrier/tile.
__global__ __launch_bounds__(512) void gemm1_kernel(const float* __restrict__ sigT,
        const float* __restrict__ w0, float* __restrict__ part, int KCH) {
    __shared__ float4 wtA[2][BG][64];
    __shared__ float4 wtB[2][BG][64];
    const int kc = blockIdx.x;
    const int k0 = kc * KCH;
    const int tid = threadIdx.x;
    const int lane = tid & 63;
    const int wvid = __builtin_amdgcn_readfirstlane(tid >> 6);  // 0..7
    const int r0 = wvid * 8;

    // prologue: stage tile 0 (thread stages k-row wvid, cols lane*8..+7)
    const float* wp0 = w0 + ((long)k0 + wvid) * N1 + lane * 8;
    float4 sA = *(const float4*)(wp0);
    float4 sB = *(const float4*)(wp0 + 4);

    float acc[8][8] = {};
    const int NT = KCH / BG;
    int cur = 0;

    for (int t = 0; t < NT; ++t) {
        wtA[cur][wvid][lane] = sA;
        wtB[cur][wvid][lane] = sB;
        __syncthreads();
        if (t + 1 < NT) {
            const float* wp = w0 + ((long)k0 + (t + 1) * BG + wvid) * N1 + lane * 8;
            sA = *(const float4*)(wp);
            sB = *(const float4*)(wp + 4);
        }
        // (a) wave-uniform z -> scalar regs, one drain
        float4 zf[BG][2];
#pragma unroll
        for (int k = 0; k < BG; ++k) {
            const float* zp = sigT + (long)(k0 + t * BG + k) * 64 + r0;
            zf[k][0] = *(const float4*)zp;
            zf[k][1] = *(const float4*)(zp + 4);
        }
        // (b) pure ds_read + FMA
#pragma unroll
        for (int k = 0; k < BG; ++k) {
            const float4 wa = wtA[cur][k][lane];
            const float4 wb = wtB[cur][k][lane];
#define ROW(R, ZV) \
            acc[R][0] += (ZV) * wa.x; acc[R][1] += (ZV) * wa.y; \
            acc[R][2] += (ZV) * wa.z; acc[R][3] += (ZV) * wa.w; \
            acc[R][4] += (ZV) * wb.x; acc[R][5] += (ZV) * wb.y; \
            acc[R][6] += (ZV) * wb.z; acc[R][7] += (ZV) * wb.w;
            ROW(0, zf[k][0].x) ROW(1, zf[k][0].y) ROW(2, zf[k][0].z) ROW(3, zf[k][0].w)
            ROW(4, zf[k][1].x) ROW(5, zf[k][1].y) ROW(6, zf[k][1].z) ROW(7, zf[k][1].w)
#undef ROW
        }
        cur ^= 1;
    }

    float* pp = part + ((long)kc * 64 + r0) * N1 + lane * 8;
#pragma unroll
    for (int r = 0; r < 8; r++) {
        *(float4*)(pp + (long)r * N1) = make_float4(acc[r][0], acc[r][1], acc[r][2], acc[r][3]);
        *(float4*)(pp + (long)r * N1 + 4) = make_float4(acc[r][4], acc[r][5], acc[r][6], acc[r][7]);
    }
}

// ---------------- Kernel 3: reduce partials + bias + sigmoid ----------------
__global__ __launch_bounds__(256) void red1_kernel(const float* __restrict__ part,
        const float* __restrict__ b0v, float* __restrict__ z1, int ksplit) {
    __shared__ float4 red[256];
    const int tid = threadIdx.x;
    const int g = tid & 31, s = tid >> 5;
    const int gg = blockIdx.x * 32 + g;
    const int per = (ksplit + 7) >> 3;
    const int ks = s * per, ke = min(ksplit, ks + per);
    float4 a = make_float4(0.f, 0.f, 0.f, 0.f);
    for (int kc = ks; kc < ke; kc++) {
        float4 pv = *(const float4*)(part + ((long)kc * 8192 + gg) * 4);
        a.x += pv.x; a.y += pv.y; a.z += pv.z; a.w += pv.w;
    }
    red[tid] = a;
    __syncthreads();
    if (tid < 128) { float4 o = red[tid + 128]; red[tid].x += o.x; red[tid].y += o.y; red[tid].z += o.z; red[tid].w += o.w; }
    __syncthreads();
    if (tid < 64) { float4 o = red[tid + 64]; red[tid].x += o.x; red[tid].y += o.y; red[tid].z += o.z; red[tid].w += o.w; }
    __syncthreads();
    if (tid < 32) {
        float4 sum = red[tid];
        float4 o = red[tid + 32];
        sum.x += o.x; sum.y += o.y; sum.z += o.z; sum.w += o.w;
        const float4 bv = *(const float4*)(b0v + (gg & 127) * 4);
        float4 r;
        r.x = 1.f / (1.f + expf(-(sum.x + bv.x)));
        r.y = 1.f / (1.f + expf(-(sum.y + bv.y)));
        r.z = 1.f / (1.f + expf(-(sum.z + bv.z)));
        r.w = 1.f / (1.f + expf(-(sum.w + bv.w)));
        *(float4*)(z1 + gg * 4) = r;
    }
}

// ---------------- Kernel 4: GEMM2 + bias + sigmoid (in-block K-split) ----------------
__global__ __launch_bounds__(256) void gemm2_kernel(const float* __restrict__ z1,
        const float* __restrict__ w1, const float* __restrict__ b1v,
        float* __restrict__ z2) {
    __shared__ float red[256];
    const int m = blockIdx.x >> 2, nq = blockIdx.x & 3;
    const int tid = threadIdx.x;
    const int c = tid & 63, s = tid >> 6;
    const int n = nq * 64 + c;
    const float* zr = z1 + m * N1 + s * 128;
    const float* wr = w1 + (long)(s * 128) * N2 + n;
    float acc = 0.f;
#pragma unroll 16
    for (int k = 0; k < 128; k++) acc += zr[k] * wr[(long)k * N2];
    red[tid] = acc;
    __syncthreads();
    if (tid < 128) red[tid] += red[tid + 128];
    __syncthreads();
    if (tid < 64) {
        float sum = red[tid] + red[tid + 64] + b1v[n];
        z2[m * N2 + n] = 1.f / (1.f + expf(-sum));
    }
}

// ---------------- Kernel 5: GEMM3 + log_softmax ----------------
__global__ __launch_bounds__(64) void head_kernel(const float* __restrict__ z2,
        const float* __restrict__ w2, const float* __restrict__ b2v,
        float* __restrict__ out) {
    const int m = blockIdx.x;
    const int tid = threadIdx.x;
    __shared__ float logits[10];
    if (tid < 10) {
        float s = b2v[tid];
        const float* zr = z2 + m * N2;
#pragma unroll 8
        for (int k = 0; k < N2; k++) s += zr[k] * w2[k * 10 + tid];
        logits[tid] = s;
    }
    __syncthreads();
    if (tid == 0) {
        float mx = logits[0];
        for (int j = 1; j < 10; j++) mx = fmaxf(mx, logits[j]);
        float sum = 0.f;
        for (int j = 0; j < 10; j++) sum += expf(logits[j] - mx);
        const float lse = mx + logf(sum);
        for (int j = 0; j < 10; j++) out[m * 10 + j] = logits[j] - lse;
    }
}

extern "C" void kernel_launch(void* const* d_in, const int* in_sizes, int n_in,
                              void* d_out, int out_size, void* d_ws, size_t ws_size,
                              hipStream_t stream) {
    const float* x  = (const float*)d_in[0];
    const float* cw = (const float*)d_in[1];
    const float* cb = (const float*)d_in[2];
    const float* w0 = (const float*)d_in[3];
    const float* b0 = (const float*)d_in[4];
    const float* w1 = (const float*)d_in[5];
    const float* b1 = (const float*)d_in[6];
    const float* w2 = (const float*)d_in[7];
    const float* b2 = (const float*)d_in[8];

    // tiered K-split by workspace: 29520 = ksplit * KCH, KCH % 8 == 0
    const size_t fixed = (size_t)NPATH * SIGCH + 64 * N1 + 64 * N2;
    int ksplit = 82, kch = 360;
    if (ws_size >= (fixed + (size_t)246 * 64 * N1) * 4)      { ksplit = 246; kch = 120; }
    else if (ws_size >= (fixed + (size_t)123 * 64 * N1) * 4) { ksplit = 123; kch = 240; }

    float* ws   = (float*)d_ws;
    float* sigT = ws;                                // 29520 x 64 (transposed)
    float* part = sigT + (long)NPATH * SIGCH;        // ksplit*64*512
    float* z1   = part + (long)ksplit * 64 * N1;     // 64*512
    float* z2   = z1 + 64 * N1;                      // 64*256
    float* out  = (float*)d_out;

    sig_kernel<<<NPATH, 256, 0, stream>>>(x, cw, cb, sigT);
    gemm1_kernel<<<ksplit, 512, 0, stream>>>(sigT, w0, part, kch);
    red1_kernel<<<256, 256, 0, stream>>>(part, b0, z1, ksplit);
    gemm2_kernel<<<256, 256, 0, stream>>>(z1, w1, b1, z2);
    head_kernel<<<64, 64, 0, stream>>>(z2, w2, b2, out);
}

// Round 10
// 92.149 us; speedup vs baseline: 1.4405x; 1.0588x over previous
//
#include <hip/hip_runtime.h>
#include <math.h>

#define TT 128
#define IN_CH 32
#define NPATH 256
#define SIGCH 7380
#define K1 29520
#define N1 512
#define N2 256
#define BG 8

// ---------------- Kernel 1: conv + time-augment + depth-4 signature ----------------
// 1024-thread block per path, 4 groups of 243 threads. Chen time-split:
// group g scans quarter [32g, 32g+32) independently (incT layout: e/f/A loads
// vectorize over time as b128 = 4 steps; block-uniform A 9-vector distributed
// via v_readlane -> off the LDS pipe). Then tree-merge: S(AB) = S(A) (x) S(B);
// B-group dumps its full sig to LDS, A-group thread merges into its regs
// (all A-side terms are its own s1,s2,s3[q],S4[q][.]). 16 waves/CU.
__global__ __launch_bounds__(1024) void sig_kernel(const float* __restrict__ x,
        const float* __restrict__ cw, const float* __restrict__ cb,
        float* __restrict__ sigT /*[29520][64]*/) {
    __shared__ float incT[9][132];
    __shared__ float sb[2][7392];
    const int p = blockIdx.x;
    const int b = p >> 2, oc = p & 3;
    const int tid = threadIdx.x;

    const float4 wv = *(const float4*)(cw + oc * 4);
    const float bias = cb[oc];
    const float* xb = x + (long)b * TT * IN_CH;

    {   // staging: one (t,ch) per thread
        const int t = tid >> 3, ch = tid & 7;
        const float4 xa = *(const float4*)(xb + t * IN_CH + ch * 4);
        float v = xa.x * wv.x + xa.y * wv.y + xa.z * wv.z + xa.w * wv.w + bias;
        if (t > 0) {
            const float4 xm = *(const float4*)(xb + (t - 1) * IN_CH + ch * 4);
            v -= xm.x * wv.x + xm.y * wv.y + xm.z * wv.z + xm.w * wv.w + bias;
        }
        incT[1 + ch][t] = v;
        if (tid < TT) incT[0][tid] = tid ? (1.f / 127.f) : 0.f;
    }
    __syncthreads();

    const int g = tid >> 8;              // group 0..3
    const int gtid = tid & 255;
    const bool act = gtid < 243;
    const int base3 = 3 * gtid;
    const int i1 = base3 / 81;
    const int i2 = (base3 / 9) % 9;
    const int i30 = base3 % 9;           // {0,3,6}
    const int lane = tid & 63;
    const int grow = min(lane, 8);

    float S4[3][9] = {};
    float s3[3] = {0.f, 0.f, 0.f};
    float s2 = 0.f, s1 = 0.f;

#define LD(R, T4) (*(const float4*)&incT[(R)][(T4)])
#define RL(XV, C) __int_as_float(__builtin_amdgcn_readlane(__float_as_int(XV), (C)))
#define STEP(GJ, E1, E2, F0, F1, F2) do { \
    const float t12 = (E1) * (E2); \
    const float s1d2 = s1 * (E2); \
    const float Ak = t12 * (1.f / 24.f) + s1d2 * (1.f / 6.f) + s2 * 0.5f; \
    const float Bk = t12 * (1.f / 6.f) + s1d2 * 0.5f + s2; \
    const float K0 = (F0) * Ak + s3[0]; \
    const float K1v = (F1) * Ak + s3[1]; \
    const float K2v = (F2) * Ak + s3[2]; \
    _Pragma("unroll") \
    for (int c = 0; c < 9; ++c) { \
        const float Ac = RL(GJ, c); \
        S4[0][c] += K0 * Ac; S4[1][c] += K1v * Ac; S4[2][c] += K2v * Ac; \
    } \
    s3[0] += Bk * (F0); s3[1] += Bk * (F1); s3[2] += Bk * (F2); \
    s2 += (E2) * (0.5f * (E1) + s1); \
    s1 += (E1); \
} while (0)

    if (act) {
        const int t0 = g * 32;
        float4 gA = LD(grow, t0), e1v = LD(i1, t0), e2v = LD(i2, t0);
        float4 f0v = LD(i30, t0), f1v = LD(i30 + 1, t0), f2v = LD(i30 + 2, t0);
        for (int j = 0; j < 8; ++j) {
            const int t4 = t0 + (((j + 1) & 7) << 2);     // last prefetch dummy
            const float4 ngA = LD(grow, t4);
            const float4 ne1 = LD(i1, t4), ne2 = LD(i2, t4);
            const float4 nf0 = LD(i30, t4), nf1 = LD(i30 + 1, t4), nf2 = LD(i30 + 2, t4);
            STEP(gA.x, e1v.x, e2v.x, f0v.x, f1v.x, f2v.x);
            STEP(gA.y, e1v.y, e2v.y, f0v.y, f1v.y, f2v.y);
            STEP(gA.z, e1v.z, e2v.z, f0v.z, f1v.z, f2v.z);
            STEP(gA.w, e1v.w, e2v.w, f0v.w, f1v.w, f2v.w);
            gA = ngA; e1v = ne1; e2v = ne2; f0v = nf0; f1v = nf1; f2v = nf2;
        }
    }
#undef STEP
#undef RL
#undef LD

    // ---- Chen tree-merge: (0,1)->0, (2,3)->2, then (0,2)->0 ----
#define WRITE_SIG(D) do { \
    float* d_ = (D); \
    if (i2 == 0 && i30 == 0) d_[i1] = s1; \
    if (i30 == 0) d_[9 + i1 * 9 + i2] = s2; \
    d_[90 + base3] = s3[0]; d_[90 + base3 + 1] = s3[1]; d_[90 + base3 + 2] = s3[2]; \
    _Pragma("unroll") \
    for (int q = 0; q < 3; ++q) \
        _Pragma("unroll") \
        for (int c = 0; c < 9; ++c) d_[819 + (base3 + q) * 9 + c] = S4[q][c]; \
} while (0)

#define MERGE_SIG(S) do { \
    const float* sB_ = (S); \
    float S1B[9]; \
    _Pragma("unroll") \
    for (int c = 0; c < 9; ++c) S1B[c] = sB_[c]; \
    _Pragma("unroll") \
    for (int q = 0; q < 3; ++q) { \
        const int i3q = i30 + q; \
        _Pragma("unroll") \
        for (int c = 0; c < 9; ++c) { \
            S4[q][c] += s3[q] * S1B[c] \
                      + s2 * sB_[9 + i3q * 9 + c] \
                      + s1 * sB_[90 + i2 * 81 + i3q * 9 + c] \
                      + sB_[819 + (base3 + q) * 9 + c]; \
        } \
    } \
    _Pragma("unroll") \
    for (int q = 0; q < 3; ++q) \
        s3[q] += s2 * S1B[i30 + q] + s1 * sB_[9 + i2 * 9 + (i30 + q)] + sB_[90 + base3 + q]; \
    s2 += s1 * S1B[i2] + sB_[9 + i1 * 9 + i2]; \
    s1 += S1B[i1]; \
} while (0)

    if (act && (g == 1 || g == 3)) WRITE_SIG(sb[g >> 1]);
    __syncthreads();
    if (act && g == 0) MERGE_SIG(sb[0]);
    if (act && g == 2) MERGE_SIG(sb[1]);
    __syncthreads();
    if (act && g == 2) WRITE_SIG(sb[0]);
    __syncthreads();
    if (act && g == 0) {
        MERGE_SIG(sb[0]);
        float* sp = sigT + (long)oc * SIGCH * 64 + b;
        if (i2 == 0 && i30 == 0) sp[(long)i1 * 64] = s1;
        if (i30 == 0) sp[(long)(9 + base3 / 9) * 64] = s2;
        sp[(long)(90 + base3 + 0) * 64] = s3[0];
        sp[(long)(90 + base3 + 1) * 64] = s3[1];
        sp[(long)(90 + base3 + 2) * 64] = s3[2];
#pragma unroll
        for (int q = 0; q < 3; q++)
#pragma unroll
            for (int l = 0; l < 9; l++)
                sp[(long)(819 + (base3 + q) * 9 + l) * 64] = S4[q][l];
    }
#undef WRITE_SIG
#undef MERGE_SIG
}

// ---------------- Kernel 2: GEMM1 partials ----------------
// Block = 64 rows x 256 cols (512 thr, 8 waves; wave owns 8 rows). Grid =
// 2 n-halves x ksplit = 492 blocks -> 2 blocks/CU = 4 waves/SIMD; cross-block
// overlap hides s_load-z chains and staging. z wave-uniform -> SGPR; w tile
// [8][256] in LDS dbuf, 1 conflict-free ds_read_b128/lane/k vs 32 FMA.
__global__ __launch_bounds__(512) void gemm1_kernel(const float* __restrict__ sigT,
        const float* __restrict__ w0, float* __restrict__ part, int KCH) {
    __shared__ float4 wt[2][BG][64];
    const int nh = blockIdx.x;            // 0/1
    const int kc = blockIdx.y;
    const int n0 = nh * 256, k0 = kc * KCH;
    const int tid = threadIdx.x;
    const int lane = tid & 63;
    const int wvid = __builtin_amdgcn_readfirstlane(tid >> 6);  // 0..7
    const int r0 = wvid * 8;
    const int sk = tid >> 6, sl = tid & 63;   // staging coords

    float4 sA = *(const float4*)(w0 + ((long)k0 + sk) * N1 + n0 + sl * 4);

    float acc[8][4] = {};
    const int NT = KCH / BG;
    int cur = 0;

    for (int t = 0; t < NT; ++t) {
        wt[cur][sk][sl] = sA;
        __syncthreads();
        if (t + 1 < NT)
            sA = *(const float4*)(w0 + ((long)k0 + (t + 1) * BG + sk) * N1 + n0 + sl * 4);
        // wave-uniform z -> scalar regs
        float4 zf[BG][2];
#pragma unroll
        for (int k = 0; k < BG; ++k) {
            const float* zp = sigT + (long)(k0 + t * BG + k) * 64 + r0;
            zf[k][0] = *(const float4*)zp;
            zf[k][1] = *(const float4*)(zp + 4);
        }
#pragma unroll
        for (int k = 0; k < BG; ++k) {
            const float4 wa = wt[cur][k][lane];
#define ROW(R, ZV) \
            acc[R][0] += (ZV) * wa.x; acc[R][1] += (ZV) * wa.y; \
            acc[R][2] += (ZV) * wa.z; acc[R][3] += (ZV) * wa.w;
            ROW(0, zf[k][0].x) ROW(1, zf[k][0].y) ROW(2, zf[k][0].z) ROW(3, zf[k][0].w)
            ROW(4, zf[k][1].x) ROW(5, zf[k][1].y) ROW(6, zf[k][1].z) ROW(7, zf[k][1].w)
#undef ROW
        }
        cur ^= 1;
    }

    float* pp = part + ((long)kc * 64 + r0) * N1 + n0 + lane * 4;
#pragma unroll
    for (int r = 0; r < 8; r++)
        *(float4*)(pp + (long)r * N1) = make_float4(acc[r][0], acc[r][1], acc[r][2], acc[r][3]);
}

// ---------------- Kernel 3: reduce partials + bias + sigmoid ----------------
__global__ __launch_bounds__(256) void red1_kernel(const float* __restrict__ part,
        const float* __restrict__ b0v, float* __restrict__ z1, int ksplit) {
    __shared__ float4 red[256];
    const int tid = threadIdx.x;
    const int g = tid & 31, s = tid >> 5;
    const int gg = blockIdx.x * 32 + g;
    const int per = (ksplit + 7) >> 3;
    const int ks = s * per, ke = min(ksplit, ks + per);
    float4 a = make_float4(0.f, 0.f, 0.f, 0.f);
    for (int kc = ks; kc < ke; kc++) {
        float4 pv = *(const float4*)(part + ((long)kc * 8192 + gg) * 4);
        a.x += pv.x; a.y += pv.y; a.z += pv.z; a.w += pv.w;
    }
    red[tid] = a;
    __syncthreads();
    if (tid < 128) { float4 o = red[tid + 128]; red[tid].x += o.x; red[tid].y += o.y; red[tid].z += o.z; red[tid].w += o.w; }
    __syncthreads();
    if (tid < 64) { float4 o = red[tid + 64]; red[tid].x += o.x; red[tid].y += o.y; red[tid].z += o.z; red[tid].w += o.w; }
    __syncthreads();
    if (tid < 32) {
        float4 sum = red[tid];
        float4 o = red[tid + 32];
        sum.x += o.x; sum.y += o.y; sum.z += o.z; sum.w += o.w;
        const float4 bv = *(const float4*)(b0v + (gg & 127) * 4);
        float4 r;
        r.x = 1.f / (1.f + expf(-(sum.x + bv.x)));
        r.y = 1.f / (1.f + expf(-(sum.y + bv.y)));
        r.z = 1.f / (1.f + expf(-(sum.z + bv.z)));
        r.w = 1.f / (1.f + expf(-(sum.w + bv.w)));
        *(float4*)(z1 + gg * 4) = r;
    }
}

// ---------------- Kernel 4: GEMM2 + bias + sigmoid (in-block K-split) ----------------
__global__ __launch_bounds__(256) void gemm2_kernel(const float* __restrict__ z1,
        const float* __restrict__ w1, const float* __restrict__ b1v,
        float* __restrict__ z2) {
    __shared__ float red[256];
    const int m = blockIdx.x >> 2, nq = blockIdx.x & 3;
    const int tid = threadIdx.x;
    const int c = tid & 63, s = tid >> 6;
    const int n = nq * 64 + c;
    const float* zr = z1 + m * N1 + s * 128;
    const float* wr = w1 + (long)(s * 128) * N2 + n;
    float acc = 0.f;
#pragma unroll 16
    for (int k = 0; k < 128; k++) acc += zr[k] * wr[(long)k * N2];
    red[tid] = acc;
    __syncthreads();
    if (tid < 128) red[tid] += red[tid + 128];
    __syncthreads();
    if (tid < 64) {
        float sum = red[tid] + red[tid + 64] + b1v[n];
        z2[m * N2 + n] = 1.f / (1.f + expf(-sum));
    }
}

// ---------------- Kernel 5: GEMM3 + log_softmax ----------------
__global__ __launch_bounds__(64) void head_kernel(const float* __restrict__ z2,
        const float* __restrict__ w2, const float* __restrict__ b2v,
        float* __restrict__ out) {
    const int m = blockIdx.x;
    const int tid = threadIdx.x;
    __shared__ float logits[10];
    if (tid < 10) {
        float s = b2v[tid];
        const float* zr = z2 + m * N2;
#pragma unroll 8
        for (int k = 0; k < N2; k++) s += zr[k] * w2[k * 10 + tid];
        logits[tid] = s;
    }
    __syncthreads();
    if (tid == 0) {
        float mx = logits[0];
        for (int j = 1; j < 10; j++) mx = fmaxf(mx, logits[j]);
        float sum = 0.f;
        for (int j = 0; j < 10; j++) sum += expf(logits[j] - mx);
        const float lse = mx + logf(sum);
        for (int j = 0; j < 10; j++) out[m * 10 + j] = logits[j] - lse;
    }
}

extern "C" void kernel_launch(void* const* d_in, const int* in_sizes, int n_in,
                              void* d_out, int out_size, void* d_ws, size_t ws_size,
                              hipStream_t stream) {
    const float* x  = (const float*)d_in[0];
    const float* cw = (const float*)d_in[1];
    const float* cb = (const float*)d_in[2];
    const float* w0 = (const float*)d_in[3];
    const float* b0 = (const float*)d_in[4];
    const float* w1 = (const float*)d_in[5];
    const float* b1 = (const float*)d_in[6];
    const float* w2 = (const float*)d_in[7];
    const float* b2 = (const float*)d_in[8];

    // tiered K-split by workspace: 29520 = ksplit * KCH, KCH % 8 == 0
    const size_t fixed = (size_t)NPATH * SIGCH + 64 * N1 + 64 * N2;
    int ksplit = 82, kch = 360;
    if (ws_size >= (fixed + (size_t)246 * 64 * N1) * 4)      { ksplit = 246; kch = 120; }
    else if (ws_size >= (fixed + (size_t)123 * 64 * N1) * 4) { ksplit = 123; kch = 240; }

    float* ws   = (float*)d_ws;
    float* sigT = ws;                                // 29520 x 64 (transposed)
    float* part = sigT + (long)NPATH * SIGCH;        // ksplit*64*512
    float* z1   = part + (long)ksplit * 64 * N1;     // 64*512
    float* z2   = z1 + 64 * N1;                      // 64*256
    float* out  = (float*)d_out;

    sig_kernel<<<NPATH, 1024, 0, stream>>>(x, cw, cb, sigT);
    gemm1_kernel<<<dim3(2, ksplit), 512, 0, stream>>>(sigT, w0, part, kch);
    red1_kernel<<<256, 256, 0, stream>>>(part, b0, z1, ksplit);
    gemm2_kernel<<<256, 256, 0, stream>>>(z1, w1, b1, z2);
    head_kernel<<<64, 64, 0, stream>>>(z2, w2, b2, out);
}